// Round 1
// baseline (1537.049 us; speedup 1.0000x reference)
//
#include <hip/hip_runtime.h>

#define T_STEPS 2000
#define NBATCH  256
#define HID     51
#define FEAT    49

__device__ __forceinline__ float rl(float v, int lane) {
    return __int_as_float(__builtin_amdgcn_readlane(__float_as_int(v), lane));
}
__device__ __forceinline__ float sigmoidf_fast(float x) {
    // 1 / (1 + 2^(-x*log2e))
    return __builtin_amdgcn_rcpf(1.0f + __builtin_amdgcn_exp2f(-1.4426950408889634f * x));
}
__device__ __forceinline__ float tanhf_fast(float x) {
    // 1 - 2/(1 + 2^(2x*log2e))
    return 1.0f - 2.0f * __builtin_amdgcn_rcpf(1.0f + __builtin_amdgcn_exp2f(2.8853900817779268f * x));
}

// Kernel 1: x_lin = relu(x @ Wl.T + bl), written into io (= d_out, reused as scratch).
__global__ void proj_kernel(const float* __restrict__ x, const float* __restrict__ Wl,
                            const float* __restrict__ bl, float* __restrict__ io) {
    int e = blockIdx.x * blockDim.x + threadIdx.x;
    if (e >= NBATCH * T_STEPS) return;
    const float* row = x + (size_t)e * FEAT;
    float acc = bl[0];
#pragma unroll
    for (int j = 0; j < FEAT; ++j) acc = fmaf(row[j], Wl[j], acc);
    io[e] = fmaxf(acc, 0.0f);
}

// Kernel 2: one wave per sample. Lane l<51 owns LSTM1 gate rows {i,f,g,o}[l];
// lane 51's accumulators compute Wih2 . h1 (LSTM2 input matvec) for free,
// pipelined one step behind. h1 broadcast via v_readlane -> SGPRs.
__global__ __launch_bounds__(64, 1) void rnn_kernel(
    float* io,  // x_lin (read, >=64 ahead) and out (write, trailing) — same buffer
    const float* __restrict__ Wih1, const float* __restrict__ Whh1,
    const float* __restrict__ bih1, const float* __restrict__ bhh1,
    const float* __restrict__ Wih2, const float* __restrict__ Whh2,
    const float* __restrict__ bih2, const float* __restrict__ bhh2,
    const float* __restrict__ Wa, const float* __restrict__ ba)
{
    const int n    = blockIdx.x;
    const int lane = threadIdx.x;
    float* xptr = io + (size_t)n * T_STEPS;
    const int total = NBATCH * T_STEPS;

    // ---- one-time per-lane weight load into registers (204 VGPRs) ----
    float w[4][HID];
    float wx[4], bias[4];
#pragma unroll
    for (int m = 0; m < 4; ++m) {
        float wxv = 0.0f, bv = 0.0f;
        if (lane < HID) {
            int row = m * HID + lane;
            wxv = Wih1[row];
            bv  = bih1[row] + bhh1[row];
#pragma unroll
            for (int k = 0; k < HID; ++k) w[m][k] = Whh1[row * HID + k];
        } else if (lane == HID) {
#pragma unroll
            for (int k = 0; k < HID; ++k) w[m][k] = Wih2[m * HID + k];
        } else {
#pragma unroll
            for (int k = 0; k < HID; ++k) w[m][k] = 0.0f;
        }
        wx[m] = wxv;
        bias[m] = bv;
    }

    // LSTM2 / output params (wave-uniform)
    float whh2v[4], b2[4];
#pragma unroll
    for (int m = 0; m < 4; ++m) { whh2v[m] = Whh2[m]; b2[m] = bih2[m] + bhh2[m]; }
    const float wav = Wa[0], bav = ba[0];

    // broadcast h1 state (SGPRs via readlane)
    float sh[HID];
#pragma unroll
    for (int k = 0; k < HID; ++k) sh[k] = 0.0f;

    float c1 = 0.0f, h1 = 0.0f;
    float h2p = 0.0f, c2p = 0.0f;

    // x_lin chunk prefetch: 64 values per lane-chunk, double buffered
    float xa = xptr[lane];        // t in [0,64)
    float xb = xptr[64 + lane];   // t in [64,128)

    for (int t = 0; t <= T_STEPS; ++t) {
        if ((t & 63) == 0 && t > 0 && t < T_STEPS) {
            xa = xb;
            int base = n * T_STEPS + t + 64 + lane;
            base = base < total ? base : (total - 1);
            xb = io[base];
        }
        float xt = rl(xa, t & 63);

        // ---- matvec: gates1(t) on lanes<51, Wih2.h1(t-1) on lane 51 ----
        float a0 = fmaf(wx[0], xt, bias[0]);
        float a1 = fmaf(wx[1], xt, bias[1]);
        float a2 = fmaf(wx[2], xt, bias[2]);
        float a3 = fmaf(wx[3], xt, bias[3]);
#pragma unroll
        for (int k = 0; k < HID; ++k) {
            float hk = sh[k];
            a0 = fmaf(w[0][k], hk, a0);
            a1 = fmaf(w[1][k], hk, a1);
            a2 = fmaf(w[2][k], hk, a2);
            a3 = fmaf(w[3][k], hk, a3);
        }

        // ---- LSTM2 step t-1 (uses Wih2.h1(t-1) from lane 51) ----
        if (t > 0) {
            float s0 = rl(a0, HID), s1 = rl(a1, HID), s2 = rl(a2, HID), s3 = rl(a3, HID);
            float g0 = s0 + b2[0] + h2p * whh2v[0];
            float g1 = s1 + b2[1] + h2p * whh2v[1];
            float g2 = s2 + b2[2] + h2p * whh2v[2];
            float g3 = s3 + b2[3] + h2p * whh2v[3];
            float i2 = sigmoidf_fast(g0);
            float f2 = sigmoidf_fast(g1);
            float gg = tanhf_fast(g2);
            float o2 = sigmoidf_fast(g3);
            float c2 = fmaf(f2, c2p, i2 * gg);
            float h2 = o2 * tanhf_fast(c2);
            c2p = c2; h2p = h2;
            float outv = fmaf(h2, wav, bav);
            if (lane == 0) xptr[t - 1] = outv;
        }

        // ---- LSTM1 nonlinearity + h1 broadcast for next step ----
        if (t < T_STEPS) {
            float ig = sigmoidf_fast(a0);
            float fg = sigmoidf_fast(a1);
            float gg = tanhf_fast(a2);
            float og = sigmoidf_fast(a3);
            c1 = fmaf(fg, c1, ig * gg);
            h1 = og * tanhf_fast(c1);
#pragma unroll
            for (int k = 0; k < HID; ++k) sh[k] = rl(h1, k);
        }
    }
}

extern "C" void kernel_launch(void* const* d_in, const int* in_sizes, int n_in,
                              void* d_out, int out_size, void* d_ws, size_t ws_size,
                              hipStream_t stream) {
    const float* x    = (const float*)d_in[0];
    const float* Wl   = (const float*)d_in[1];
    const float* bl   = (const float*)d_in[2];
    const float* Wih1 = (const float*)d_in[3];
    const float* Whh1 = (const float*)d_in[4];
    const float* bih1 = (const float*)d_in[5];
    const float* bhh1 = (const float*)d_in[6];
    const float* Wih2 = (const float*)d_in[7];
    const float* Whh2 = (const float*)d_in[8];
    const float* bih2 = (const float*)d_in[9];
    const float* bhh2 = (const float*)d_in[10];
    const float* Wa   = (const float*)d_in[11];
    const float* ba   = (const float*)d_in[12];
    float* io = (float*)d_out;

    proj_kernel<<<(NBATCH * T_STEPS + 255) / 256, 256, 0, stream>>>(x, Wl, bl, io);
    rnn_kernel<<<NBATCH, 64, 0, stream>>>(io, Wih1, Whh1, bih1, bhh1,
                                          Wih2, Whh2, bih2, bhh2, Wa, ba);
}

// Round 2
// 1507.666 us; speedup vs baseline: 1.0195x; 1.0195x over previous
//
#include <hip/hip_runtime.h>

#define T_STEPS 2000
#define NBATCH  256
#define HID     51
#define FEAT    49

typedef float v2f __attribute__((ext_vector_type(2)));

__device__ __forceinline__ float rl(float v, int lane) {
    return __int_as_float(__builtin_amdgcn_readlane(__float_as_int(v), lane));
}
__device__ __forceinline__ float sigmoidf_fast(float x) {
    // 1 / (1 + 2^(-x*log2e))
    return __builtin_amdgcn_rcpf(1.0f + __builtin_amdgcn_exp2f(-1.4426950408889634f * x));
}
__device__ __forceinline__ float tanhf_fast(float x) {
    // 1 - 2/(1 + 2^(2x*log2e))
    return 1.0f - 2.0f * __builtin_amdgcn_rcpf(1.0f + __builtin_amdgcn_exp2f(2.8853900817779268f * x));
}

// Kernel 1: x_lin = relu(x @ Wl.T + bl) -> io (= d_out reused as scratch).
// LDS-tiled so global reads are fully coalesced float4.
__global__ __launch_bounds__(256) void proj_kernel(const float* __restrict__ x,
                                                   const float* __restrict__ Wl,
                                                   const float* __restrict__ bl,
                                                   float* __restrict__ io) {
    __shared__ float tile[256 * FEAT];  // 50176 B
    const int base = blockIdx.x * 256;
    const float4* src4 = (const float4*)(x + (size_t)base * FEAT);
    float4* t4 = (float4*)tile;
    // 256*49/4 = 3136 float4s per block
    for (int i = threadIdx.x; i < (256 * FEAT) / 4; i += 256) t4[i] = src4[i];
    __syncthreads();
    const float* row = &tile[threadIdx.x * FEAT];
    float acc = bl[0];
#pragma unroll
    for (int j = 0; j < FEAT; ++j) acc = fmaf(row[j], Wl[j], acc);
    io[base + threadIdx.x] = fmaxf(acc, 0.0f);
}

// Kernel 2: one wave per sample. Lane l<51 owns LSTM1 gate rows {i,f,g,o}[l]
// packed as float2 pairs (i,f)/(g,o) for v_pk_fma_f32; lane 51's accumulators
// compute Wih2 . h1 (LSTM2 input matvec) for free, pipelined one step behind.
// Weights pinned in VGPRs via empty asm (defeats load rematerialization).
__global__ __launch_bounds__(64, 1) void rnn_kernel(
    float* io,
    const float* __restrict__ Wih1, const float* __restrict__ Whh1,
    const float* __restrict__ bih1, const float* __restrict__ bhh1,
    const float* __restrict__ Wih2, const float* __restrict__ Whh2,
    const float* __restrict__ bih2, const float* __restrict__ bhh2,
    const float* __restrict__ Wa, const float* __restrict__ ba)
{
    const int n    = blockIdx.x;
    const int lane = threadIdx.x;
    float* xptr = io + (size_t)n * T_STEPS;
    const int total = NBATCH * T_STEPS;

    // ---- one-time per-lane weight load into registers (204 VGPRs) ----
    v2f wif[HID], wgo[HID];     // (i,f) and (g,o) recurrent weight pairs
    v2f wx_if, wx_go, b_if, b_go;

    if (lane < HID) {
#pragma unroll
        for (int k = 0; k < HID; ++k) {
            float w0 = Whh1[(0 * HID + lane) * HID + k];
            float w1 = Whh1[(1 * HID + lane) * HID + k];
            float w2 = Whh1[(2 * HID + lane) * HID + k];
            float w3 = Whh1[(3 * HID + lane) * HID + k];
            asm volatile("" : "+v"(w0), "+v"(w1), "+v"(w2), "+v"(w3));
            wif[k] = (v2f){w0, w1};
            wgo[k] = (v2f){w2, w3};
        }
        wx_if = (v2f){Wih1[0 * HID + lane], Wih1[1 * HID + lane]};
        wx_go = (v2f){Wih1[2 * HID + lane], Wih1[3 * HID + lane]};
        b_if  = (v2f){bih1[0 * HID + lane] + bhh1[0 * HID + lane],
                      bih1[1 * HID + lane] + bhh1[1 * HID + lane]};
        b_go  = (v2f){bih1[2 * HID + lane] + bhh1[2 * HID + lane],
                      bih1[3 * HID + lane] + bhh1[3 * HID + lane]};
    } else if (lane == HID) {
#pragma unroll
        for (int k = 0; k < HID; ++k) {
            float w0 = Wih2[0 * HID + k];
            float w1 = Wih2[1 * HID + k];
            float w2 = Wih2[2 * HID + k];
            float w3 = Wih2[3 * HID + k];
            asm volatile("" : "+v"(w0), "+v"(w1), "+v"(w2), "+v"(w3));
            wif[k] = (v2f){w0, w1};
            wgo[k] = (v2f){w2, w3};
        }
        wx_if = (v2f){0.0f, 0.0f}; wx_go = (v2f){0.0f, 0.0f};
        b_if  = (v2f){0.0f, 0.0f}; b_go  = (v2f){0.0f, 0.0f};
    } else {
#pragma unroll
        for (int k = 0; k < HID; ++k) {
            wif[k] = (v2f){0.0f, 0.0f};
            wgo[k] = (v2f){0.0f, 0.0f};
        }
        wx_if = (v2f){0.0f, 0.0f}; wx_go = (v2f){0.0f, 0.0f};
        b_if  = (v2f){0.0f, 0.0f}; b_go  = (v2f){0.0f, 0.0f};
    }

    // LSTM2 / output params (wave-uniform)
    float whh2v[4], b2[4];
#pragma unroll
    for (int m = 0; m < 4; ++m) { whh2v[m] = Whh2[m]; b2[m] = bih2[m] + bhh2[m]; }
    const float wav = Wa[0], bav = ba[0];

    // broadcast h1 state (SGPRs via readlane)
    float sh[HID];
#pragma unroll
    for (int k = 0; k < HID; ++k) sh[k] = 0.0f;

    float c1 = 0.0f, h1 = 0.0f;
    float h2p = 0.0f, c2p = 0.0f;

    // x_lin chunk prefetch: 64 values per lane-chunk, double buffered
    float xa = xptr[lane];        // t in [0,64)
    float xb = xptr[64 + lane];   // t in [64,128)

#pragma unroll 1
    for (int t = 0; t <= T_STEPS; ++t) {
        if ((t & 63) == 0 && t > 0 && t < T_STEPS) {
            xa = xb;
            int base = n * T_STEPS + t + 64 + lane;
            base = base < total ? base : (total - 1);
            xb = io[base];
        }
        float xt = rl(xa, t & 63);

        // ---- matvec: gates1(t) on lanes<51, Wih2.h1(t-1) on lane 51 ----
        v2f xts = (v2f){xt, xt};
        v2f aif = wx_if * xts + b_if;
        v2f ago = wx_go * xts + b_go;
#pragma unroll
        for (int k = 0; k < HID; ++k) {
            float hk = sh[k];
            v2f hv = (v2f){hk, hk};
            aif += wif[k] * hv;
            ago += wgo[k] * hv;
        }

        // ---- LSTM2 step t-1 (uses Wih2.h1(t-1) from lane 51) ----
        if (t > 0) {
            float s0 = rl(aif.x, HID), s1 = rl(aif.y, HID);
            float s2 = rl(ago.x, HID), s3 = rl(ago.y, HID);
            float g0 = s0 + b2[0] + h2p * whh2v[0];
            float g1 = s1 + b2[1] + h2p * whh2v[1];
            float g2 = s2 + b2[2] + h2p * whh2v[2];
            float g3 = s3 + b2[3] + h2p * whh2v[3];
            float i2 = sigmoidf_fast(g0);
            float f2 = sigmoidf_fast(g1);
            float gg = tanhf_fast(g2);
            float o2 = sigmoidf_fast(g3);
            float c2 = fmaf(f2, c2p, i2 * gg);
            float h2 = o2 * tanhf_fast(c2);
            c2p = c2; h2p = h2;
            float outv = fmaf(h2, wav, bav);
            if (lane == 0) xptr[t - 1] = outv;
        }

        // ---- LSTM1 nonlinearity + h1 broadcast for next step ----
        if (t < T_STEPS) {
            float ig = sigmoidf_fast(aif.x);
            float fg = sigmoidf_fast(aif.y);
            float gg = tanhf_fast(ago.x);
            float og = sigmoidf_fast(ago.y);
            c1 = fmaf(fg, c1, ig * gg);
            h1 = og * tanhf_fast(c1);
#pragma unroll
            for (int k = 0; k < HID; ++k) sh[k] = rl(h1, k);
        }
    }
}

extern "C" void kernel_launch(void* const* d_in, const int* in_sizes, int n_in,
                              void* d_out, int out_size, void* d_ws, size_t ws_size,
                              hipStream_t stream) {
    const float* x    = (const float*)d_in[0];
    const float* Wl   = (const float*)d_in[1];
    const float* bl   = (const float*)d_in[2];
    const float* Wih1 = (const float*)d_in[3];
    const float* Whh1 = (const float*)d_in[4];
    const float* bih1 = (const float*)d_in[5];
    const float* bhh1 = (const float*)d_in[6];
    const float* Wih2 = (const float*)d_in[7];
    const float* Whh2 = (const float*)d_in[8];
    const float* bih2 = (const float*)d_in[9];
    const float* bhh2 = (const float*)d_in[10];
    const float* Wa   = (const float*)d_in[11];
    const float* ba   = (const float*)d_in[12];
    float* io = (float*)d_out;

    proj_kernel<<<(NBATCH * T_STEPS) / 256, 256, 0, stream>>>(x, Wl, bl, io);
    rnn_kernel<<<NBATCH, 64, 0, stream>>>(io, Wih1, Whh1, bih1, bhh1,
                                          Wih2, Whh2, bih2, bhh2, Wa, ba);
}

// Round 3
// 1303.542 us; speedup vs baseline: 1.1791x; 1.1566x over previous
//
#include <hip/hip_runtime.h>

#define T_STEPS 2000
#define NBATCH  256
#define HID     51
#define KW      52   // 51 h1 terms + 1 h2 term (lane 51's Whh2 column)
#define FEAT    49

typedef float v2f __attribute__((ext_vector_type(2)));

__device__ __forceinline__ float rl(float v, int lane) {
    return __int_as_float(__builtin_amdgcn_readlane(__float_as_int(v), lane));
}
__device__ __forceinline__ float sigmoidf_fast(float x) {
    return __builtin_amdgcn_rcpf(1.0f + __builtin_amdgcn_exp2f(-1.4426950408889634f * x));
}
__device__ __forceinline__ float tanhf_fast(float x) {
    return 1.0f - 2.0f * __builtin_amdgcn_rcpf(1.0f + __builtin_amdgcn_exp2f(2.8853900817779268f * x));
}

// Kernel 1: x_lin = relu(x @ Wl.T + bl) -> io (= d_out reused as scratch).
__global__ __launch_bounds__(256) void proj_kernel(const float* __restrict__ x,
                                                   const float* __restrict__ Wl,
                                                   const float* __restrict__ bl,
                                                   float* __restrict__ io) {
    __shared__ float tile[256 * FEAT];
    const int base = blockIdx.x * 256;
    const float4* src4 = (const float4*)(x + (size_t)base * FEAT);
    float4* t4 = (float4*)tile;
    for (int i = threadIdx.x; i < (256 * FEAT) / 4; i += 256) t4[i] = src4[i];
    __syncthreads();
    const float* row = &tile[threadIdx.x * FEAT];
    float acc = bl[0];
#pragma unroll
    for (int j = 0; j < FEAT; ++j) acc = fmaf(row[j], Wl[j], acc);
    io[base + threadIdx.x] = fmaxf(acc, 0.0f);
}

// Kernel 2: one wave per sample. Lanes 0..50 carry LSTM1 rows; lane 51 carries
// LSTM2 (its gates flow through the SAME pk-fma matvec and the SAME
// sigmoid/tanh/c/h update — zero extra per-step code, one step skewed).
// amdgpu_waves_per_eu(1,1) unlocks the 512-VGPR budget so the 208 weight
// floats stay register-resident (round-2's 116-VGPR cap = default 4-wave/EU
// target; that was the whole bottleneck).
__global__ __attribute__((amdgpu_flat_work_group_size(64, 64), amdgpu_waves_per_eu(1, 1)))
void rnn_kernel(
    float* io,
    const float* __restrict__ Wih1, const float* __restrict__ Whh1,
    const float* __restrict__ bih1, const float* __restrict__ bhh1,
    const float* __restrict__ Wih2, const float* __restrict__ Whh2,
    const float* __restrict__ bih2, const float* __restrict__ bhh2,
    const float* __restrict__ Wa, const float* __restrict__ ba)
{
    const int n    = blockIdx.x;
    const int lane = threadIdx.x;
    float* xptr = io + (size_t)n * T_STEPS;
    const int total = NBATCH * T_STEPS;

    // ---- one-time per-lane weight load into registers (208 VGPRs) ----
    v2f wif[KW], wgo[KW];
    {
        const float *s0, *s1, *s2, *s3;
        float msk;
        if (lane < HID) {
            s0 = Whh1 + (0 * HID + lane) * HID;
            s1 = Whh1 + (1 * HID + lane) * HID;
            s2 = Whh1 + (2 * HID + lane) * HID;
            s3 = Whh1 + (3 * HID + lane) * HID;
            msk = 1.0f;
        } else {
            s0 = Wih2 + 0 * HID; s1 = Wih2 + 1 * HID;
            s2 = Wih2 + 2 * HID; s3 = Wih2 + 3 * HID;
            msk = (lane == HID) ? 1.0f : 0.0f;
        }
#pragma unroll
        for (int k = 0; k < HID; ++k) {
            float w0 = s0[k] * msk, w1 = s1[k] * msk, w2 = s2[k] * msk, w3 = s3[k] * msk;
            asm volatile("" : "+v"(w0), "+v"(w1), "+v"(w2), "+v"(w3));
            wif[k] = (v2f){w0, w1};
            wgo[k] = (v2f){w2, w3};
        }
        float m2 = (lane == HID) ? 1.0f : 0.0f;
        float w0 = Whh2[0] * m2, w1 = Whh2[1] * m2, w2 = Whh2[2] * m2, w3 = Whh2[3] * m2;
        asm volatile("" : "+v"(w0), "+v"(w1), "+v"(w2), "+v"(w3));
        wif[HID] = (v2f){w0, w1};
        wgo[HID] = (v2f){w2, w3};
    }

    v2f wx_if = (v2f){0.0f, 0.0f}, wx_go = (v2f){0.0f, 0.0f};
    v2f b_if  = (v2f){0.0f, 0.0f}, b_go  = (v2f){0.0f, 0.0f};
    if (lane < HID) {
        wx_if = (v2f){Wih1[lane],           Wih1[HID + lane]};
        wx_go = (v2f){Wih1[2 * HID + lane], Wih1[3 * HID + lane]};
        b_if  = (v2f){bih1[lane] + bhh1[lane],
                      bih1[HID + lane] + bhh1[HID + lane]};
        b_go  = (v2f){bih1[2 * HID + lane] + bhh1[2 * HID + lane],
                      bih1[3 * HID + lane] + bhh1[3 * HID + lane]};
    } else if (lane == HID) {
        b_if  = (v2f){bih2[0] + bhh2[0], bih2[1] + bhh2[1]};
        b_go  = (v2f){bih2[2] + bhh2[2], bih2[3] + bhh2[3]};
    }
    const float wav = Wa[0], bav = ba[0];

    // broadcast state: sh[k<51] = h1[k], sh[51] = h2 (uniform -> SGPRs)
    float sh[KW];
#pragma unroll
    for (int k = 0; k < KW; ++k) sh[k] = 0.0f;

    float c = 0.0f, h = 0.0f;

    // x_lin chunk prefetch: 64 values per lane-chunk, double buffered
    float xa = xptr[lane];
    float xb = xptr[64 + lane];

#pragma unroll 1
    for (int t = 0; t <= T_STEPS; ++t) {
        if ((t & 63) == 0 && t > 0 && t < T_STEPS) {
            xa = xb;
            int bidx = n * T_STEPS + t + 64 + lane;
            bidx = bidx < total ? bidx : (total - 1);
            xb = io[bidx];
        }
        float xt = rl(xa, t & 63);

        // ---- matvec: 4 gate rows/lane as two v2f chains x2 (split for dep latency) ----
        v2f xv = (v2f){xt, xt};
        v2f a0 = b_if + wx_if * xv, a1 = (v2f){0.0f, 0.0f};
        v2f g0 = b_go + wx_go * xv, g1 = (v2f){0.0f, 0.0f};
#pragma unroll
        for (int k = 0; k < KW; k += 2) {
            v2f h0 = (v2f){sh[k], sh[k]};
            a0 += wif[k] * h0;
            g0 += wgo[k] * h0;
            v2f h1v = (v2f){sh[k + 1], sh[k + 1]};
            a1 += wif[k + 1] * h1v;
            g1 += wgo[k + 1] * h1v;
        }
        v2f aif = a0 + a1, ago = g0 + g1;

        // ---- shared nonlinearity + state update (lane51 = LSTM2) ----
        float ig = sigmoidf_fast(aif.x);
        float fg = sigmoidf_fast(aif.y);
        float gg = tanhf_fast(ago.x);
        float og = sigmoidf_fast(ago.y);
        c = fmaf(fg, c, ig * gg);
        h = og * tanhf_fast(c);
        if (t == 0 && lane >= HID) { c = 0.0f; h = 0.0f; }  // LSTM2 zero init (skewed)

        float outv = fmaf(h, wav, bav);
        if (t > 0 && lane == HID) xptr[t - 1] = outv;

#pragma unroll
        for (int k = 0; k < KW; ++k) sh[k] = rl(h, k);
    }
}

extern "C" void kernel_launch(void* const* d_in, const int* in_sizes, int n_in,
                              void* d_out, int out_size, void* d_ws, size_t ws_size,
                              hipStream_t stream) {
    const float* x    = (const float*)d_in[0];
    const float* Wl   = (const float*)d_in[1];
    const float* bl   = (const float*)d_in[2];
    const float* Wih1 = (const float*)d_in[3];
    const float* Whh1 = (const float*)d_in[4];
    const float* bih1 = (const float*)d_in[5];
    const float* bhh1 = (const float*)d_in[6];
    const float* Wih2 = (const float*)d_in[7];
    const float* Whh2 = (const float*)d_in[8];
    const float* bih2 = (const float*)d_in[9];
    const float* bhh2 = (const float*)d_in[10];
    const float* Wa   = (const float*)d_in[11];
    const float* ba   = (const float*)d_in[12];
    float* io = (float*)d_out;

    proj_kernel<<<(NBATCH * T_STEPS) / 256, 256, 0, stream>>>(x, Wl, bl, io);
    rnn_kernel<<<NBATCH, 64, 0, stream>>>(io, Wih1, Whh1, bih1, bhh1,
                                          Wih2, Whh2, bih2, bhh2, Wa, ba);
}